// Round 6
// baseline (332.288 us; speedup 1.0000x reference)
//
#include <hip/hip_runtime.h>
#include <hip/hip_bf16.h>

using f16x8 = __attribute__((ext_vector_type(8))) _Float16;
using f32x4 = __attribute__((ext_vector_type(4))) float;

extern "C" __device__ float __ocml_native_exp2_f32(float);

static constexpr int Bc = 4, Sc = 4096, INc = 1024, Nc = 1024, OUTc = 1024;
static constexpr int Mc = Bc * Sc;               // 16384
#define K2LE 2.8853900817779268f                 // 2 * log2(e)

__device__ __forceinline__ unsigned short f2h(float f) {
    return __builtin_bit_cast(unsigned short, (_Float16)f);
}
__device__ __forceinline__ float h2f(unsigned short s) {
    return (float)__builtin_bit_cast(_Float16, s);
}

// ---------------- fp32 -> (f16 hi, f16 lo) split, vectorized ----------------
// x ~ N(0,1): hi residuals (~2e-4) are in f16 normal range -> no denormal hazard.
__global__ __launch_bounds__(256) void split2h(const float* __restrict__ in,
                                               unsigned short* __restrict__ hi,
                                               unsigned short* __restrict__ lo, int n4) {
    int i = blockIdx.x * blockDim.x + threadIdx.x;
    if (i >= n4) return;
    float4 v = reinterpret_cast<const float4*>(in)[i];
    ushort4 h, l;
    h.x = f2h(v.x); l.x = f2h(v.x - h2f(h.x));
    h.y = f2h(v.y); l.y = f2h(v.y - h2f(h.y));
    h.z = f2h(v.z); l.z = f2h(v.z - h2f(h.z));
    h.w = f2h(v.w); l.w = f2h(v.w - h2f(h.w));
    reinterpret_cast<ushort4*>(hi)[i] = h;
    reinterpret_cast<ushort4*>(lo)[i] = l;
}

// ---------------- transpose + f16 convert: out[c][r] = f16(in[r][c]) ----------------
__global__ __launch_bounds__(256) void tr_h(const float* __restrict__ in,
                                            unsigned short* __restrict__ out, int R, int C) {
    __shared__ float t[32][33];
    int c0 = blockIdx.x * 32, r0 = blockIdx.y * 32;
    for (int i = threadIdx.y; i < 32; i += 8)
        t[i][threadIdx.x] = in[(size_t)(r0 + i) * C + c0 + threadIdx.x];
    __syncthreads();
    for (int i = threadIdx.y; i < 32; i += 8)
        out[(size_t)(c0 + i) * R + r0 + threadIdx.x] = f2h(t[threadIdx.x][i]);
}

// ---------------- f16 MFMA GEMM: C[M,N] fp32 = A[M,K] * BT[N,K]^T ----------------
// MODE 0: single-A, no epilogue (GEMM2).
// MODE 1: split-A (Ah+Al), epilogue C = K2LE*(acc + bi + hs*u + w)  (GEMM1).
// Both: XCD-chunked blockIdx swizzle (grid % 8 == 0).
template<int MODE>
__global__ __launch_bounds__(256) void gemm_h(const unsigned short* __restrict__ Ah,
                                              const unsigned short* __restrict__ Al,
                                              const unsigned short* __restrict__ BT,
                                              float* __restrict__ C, int N, int K,
                                              const float* __restrict__ bi,
                                              const float* __restrict__ u,
                                              const float* __restrict__ hs,
                                              const float* __restrict__ wv) {
    constexpr int BM = 128, BN = 128, BK = 64;
    __shared__ alignas(16) unsigned short Ash[BM * BK];
    __shared__ alignas(16) unsigned short Asl[MODE ? BM * BK : 1];
    __shared__ alignas(16) unsigned short Bs[BN * BK];
    const int nb = N >> 7;
    // T1: XCD-chunked swizzle — consecutive logical tiles land on the same XCD L2.
    const int cpx = (int)gridDim.x >> 3;
    const int wg = (blockIdx.x & 7) * cpx + (blockIdx.x >> 3);
    const int bm = wg / nb, bn = wg % nb;
    const int tid = threadIdx.x;
    const int w = tid >> 6, l = tid & 63;
    const int wr = w >> 1, wc = w & 1;
    const int r = l & 15, g4 = l >> 4;
    const int lrow = l >> 3, lcol = (l & 7) * 8;

    f32x4 acc[4][4] = {};

    const size_t aoff = (size_t)bm * BM * K;
    const size_t boff = (size_t)bn * BN * K;

    for (int k0 = 0; k0 < K; k0 += BK) {
        __syncthreads();
#pragma unroll
        for (int i = 0; i < 4; i++) {
            size_t grow = (size_t)((w * 4 + i) * 8 + lrow) * K + (k0 + lcol);
            int ldst = (w * 4 + i) * 512;
            __builtin_amdgcn_global_load_lds(
                (const __attribute__((address_space(1))) void*)(Ah + aoff + grow),
                (__attribute__((address_space(3))) void*)(Ash + ldst), 16, 0, 0);
            if (MODE)
                __builtin_amdgcn_global_load_lds(
                    (const __attribute__((address_space(1))) void*)(Al + aoff + grow),
                    (__attribute__((address_space(3))) void*)(Asl + ldst), 16, 0, 0);
            __builtin_amdgcn_global_load_lds(
                (const __attribute__((address_space(1))) void*)(BT + boff + grow),
                (__attribute__((address_space(3))) void*)(Bs + ldst), 16, 0, 0);
        }
        __syncthreads();
#pragma unroll
        for (int kk = 0; kk < BK; kk += 32) {
            f16x8 ah[4], al[4], bf[4];
#pragma unroll
            for (int m = 0; m < 4; m++) {
                int off = (wr * 64 + m * 16 + r) * BK + kk + g4 * 8;
                ah[m] = *reinterpret_cast<const f16x8*>(Ash + off);
                if (MODE) al[m] = *reinterpret_cast<const f16x8*>(Asl + off);
            }
#pragma unroll
            for (int n = 0; n < 4; n++)
                bf[n] = *reinterpret_cast<const f16x8*>(Bs + (wc * 64 + n * 16 + r) * BK + kk + g4 * 8);
#pragma unroll
            for (int m = 0; m < 4; m++)
#pragma unroll
                for (int n = 0; n < 4; n++) {
                    acc[m][n] = __builtin_amdgcn_mfma_f32_16x16x32_f16(ah[m], bf[n], acc[m][n], 0, 0, 0);
                    if (MODE)
                        acc[m][n] = __builtin_amdgcn_mfma_f32_16x16x32_f16(al[m], bf[n], acc[m][n], 0, 0, 0);
                }
        }
    }

    const int bbase = MODE ? ((bm * BM) / Sc) * Nc : 0;   // batch uniform per block
#pragma unroll
    for (int m = 0; m < 4; m++) {
        int row = bm * BM + wr * 64 + m * 16 + g4 * 4;
#pragma unroll
        for (int n = 0; n < 4; n++) {
            int col = bn * BN + wc * 64 + n * 16 + r;
            float extra = 0.f;
            if (MODE) extra = bi[col] + hs[bbase + col] * u[col] + wv[col];
#pragma unroll
            for (int q = 0; q < 4; q++) {
                float v = acc[m][n][q];
                if (MODE) v = (v + extra) * K2LE;
                C[(size_t)(row + q) * N + col] = v;
            }
        }
    }
}

// ---------------- sequential tanh recurrence: producer-consumer, 2 chains/lane ----------------
// xp holds K2LE*(x@Wi + bi + hippo + w). Producer wave: each lane runs TWO
// independent (b,n) chains (n0+l and n0+64+l) interleaved — the second chain's
// ops fill the issue slots the first chain's exp/rcp latency leaves empty.
// Consumer wave drains 32x128 rr values per chunk: h = 1-2rr, f16 pack,
// coalesced dwordx4 stores. Double-buffered LDS; lgkmcnt-only fence on the
// producer so its x-prefetch VMEM queue is never drained.
static constexpr int SROW = 132;   // floats per LDS row (128 + 4 pad; bank-spread for b128 reads)

template<bool PREF>
__device__ __forceinline__ void sblk2(const float* __restrict__ xrowA,
                                      const float* __restrict__ xrowB,
                                      float (&curA)[32], float (&curB)[32],
                                      float (&nxtA)[32], float (&nxtB)[32],
                                      float* __restrict__ hbl, int tblk,
                                      float nw2A, float nw2B, float& rrA, float& rrB) {
#pragma unroll
    for (int d = 0; d < 32; d++) {
        if (PREF) {
            nxtA[d] = xrowA[(size_t)(tblk + 32 + d) << 10];   // 1 chunk ahead
            nxtB[d] = xrowB[(size_t)(tblk + 32 + d) << 10];
        }
        float zA = fmaf(nw2A, rrA, curA[d]);
        float zB = fmaf(nw2B, rrB, curB[d]);
        float eA = __ocml_native_exp2_f32(zA);        // v_exp_f32
        float eB = __ocml_native_exp2_f32(zB);
        rrA = __builtin_amdgcn_rcpf(eA + 1.f);        // v_rcp_f32
        rrB = __builtin_amdgcn_rcpf(eB + 1.f);
        hbl[d * SROW] = rrA;                          // ds_write_b32, imm offsets
        hbl[d * SROW + 64] = rrB;
    }
    asm volatile("s_waitcnt lgkmcnt(0)" ::: "memory");
    __builtin_amdgcn_s_barrier();
}

__device__ __forceinline__ unsigned int pk2(float a, float b) {
    return ((unsigned int)f2h(fmaf(-2.f, b, 1.f)) << 16) | f2h(fmaf(-2.f, a, 1.f));
}

__device__ __forceinline__ void drain128(const float* __restrict__ buf, int tblk,
                                         unsigned short* __restrict__ srow, int n0, int l) {
    __builtin_amdgcn_s_barrier();
    asm volatile("" ::: "memory");
    int row8 = l >> 3, cg = l & 7;
#pragma unroll
    for (int i = 0; i < 8; i++) {
        int half = i >> 2;                  // 0: cols 0-63, 1: cols 64-127
        int row = (i & 3) * 8 + row8;
        int cbase = half * 64 + cg * 8;
        float4 a = *reinterpret_cast<const float4*>(&buf[row * SROW + cbase]);
        float4 b = *reinterpret_cast<const float4*>(&buf[row * SROW + cbase + 4]);
        uint4 v = { pk2(a.x, a.y), pk2(a.z, a.w), pk2(b.x, b.y), pk2(b.z, b.w) };
        *reinterpret_cast<uint4*>(&srow[((size_t)(tblk + row) << 10) + n0 + cbase]) = v;
    }
}

__global__ __launch_bounds__(128) void scan5(const float* __restrict__ xp,
                                             const float* __restrict__ w,
                                             const float* __restrict__ h0,
                                             unsigned short* __restrict__ states,
                                             float* __restrict__ out_state) {
    __shared__ alignas(16) float hb[2][32 * SROW];     // 33 KiB
    const int l = threadIdx.x & 63;
    const int wave = threadIdx.x >> 6;
    const int b = blockIdx.x >> 3;                     // 32 blocks: 4 b x 8 ngroups
    const int n0 = (blockIdx.x & 7) * 128;

    if (wave == 0) {
        const int nA = n0 + l, nB = n0 + 64 + l;
        const int tidA = (b << 10) + nA, tidB = (b << 10) + nB;
        float nw2A = w[nA] * (-2.f * K2LE);
        float nw2B = w[nB] * (-2.f * K2LE);
        float rrA = 0.5f - 0.5f * h0[tidA];            // h = 1 - 2*rr
        float rrB = 0.5f - 0.5f * h0[tidB];
        const float* xrowA = xp + ((size_t)b << 22) + nA;
        const float* xrowB = xrowA + 64;
        float* hbl0 = &hb[0][l];
        float* hbl1 = &hb[1][l];

        float xaA[32], xaB[32], xbA[32], xbB[32];
#pragma unroll
        for (int d = 0; d < 32; d++) {
            xaA[d] = xrowA[(size_t)d << 10];
            xaB[d] = xrowB[(size_t)d << 10];
        }

        int t = 0;
        for (; t + 64 < Sc; t += 64) {
            sblk2<true>(xrowA, xrowB, xaA, xaB, xbA, xbB, hbl0, t, nw2A, nw2B, rrA, rrB);
            sblk2<true>(xrowA, xrowB, xbA, xbB, xaA, xaB, hbl1, t + 32, nw2A, nw2B, rrA, rrB);
        }
        sblk2<true >(xrowA, xrowB, xaA, xaB, xbA, xbB, hbl0, t, nw2A, nw2B, rrA, rrB);
        sblk2<false>(xrowA, xrowB, xbA, xbB, xaA, xaB, hbl1, t + 32, nw2A, nw2B, rrA, rrB);
        out_state[tidA] = fmaf(-2.f, rrA, 1.f);
        out_state[tidB] = fmaf(-2.f, rrB, 1.f);
    } else {
        unsigned short* srow = states + ((size_t)b << 22);
        for (int t = 0; t < Sc; t += 64) {
            drain128(hb[0], t, srow, n0, l);
            drain128(hb[1], t + 32, srow, n0, l);
        }
    }
}

extern "C" void kernel_launch(void* const* d_in, const int* in_sizes, int n_in,
                              void* d_out, int out_size, void* d_ws, size_t ws_size,
                              hipStream_t stream) {
    const float* x  = (const float*)d_in[0];
    const float* Wi = (const float*)d_in[1];
    const float* bi = (const float*)d_in[2];
    const float* w  = (const float*)d_in[3];
    const float* u  = (const float*)d_in[4];
    const float* Wo = (const float*)d_in[5];
    const float* h0 = (const float*)d_in[6];
    const float* hs = (const float*)d_in[7];
    float* out = (float*)d_out;                          // [M, OUT] fp32
    float* out_state = out + (size_t)Mc * OUTc;          // [B, N] fp32
    float* xp = out;                                     // xp scratch lives in d_out (dead before GEMM2)

    // ws layout (68 MiB): xh 32M | xl 32M | WiT 2M | WoT 2M ; states (f16) reuse xh
    char* ws = (char*)d_ws;
    unsigned short* xh  = (unsigned short*)ws;
    unsigned short* xl  = (unsigned short*)(ws + 33554432);
    unsigned short* WiT = (unsigned short*)(ws + 67108864);
    unsigned short* WoT = (unsigned short*)(ws + 69206016);
    unsigned short* states = xh;                         // xh dead after gemm1

    split2h<<<(Mc * INc / 4 + 255) / 256, 256, 0, stream>>>(x, xh, xl, Mc * INc / 4);
    dim3 tb(32, 8);
    tr_h<<<dim3(Nc / 32, INc / 32), tb, 0, stream>>>(Wi, WiT, INc, Nc);
    tr_h<<<dim3(OUTc / 32, Nc / 32), tb, 0, stream>>>(Wo, WoT, Nc, OUTc);

    gemm_h<1><<<(Mc / 128) * (Nc / 128), 256, 0, stream>>>(xh, xl, WiT, xp, Nc, INc, bi, u, hs, w);
    scan5<<<32, 128, 0, stream>>>(xp, w, h0, states, out_state);
    gemm_h<0><<<(Mc / 128) * (OUTc / 128), 256, 0, stream>>>(states, nullptr, WoT, out, OUTc, Nc,
                                                             nullptr, nullptr, nullptr, nullptr);
}